// Round 1
// baseline (1322.465 us; speedup 1.0000x reference)
//
#include <hip/hip_runtime.h>

#define Nn 100000
#define Ne 1600000
#define Fi 32
#define Hd 64
#define Ll 4
#define Gg 256
#define BN_EPS 1e-5f

// ---------------- setup kernels ----------------

__global__ void k_deg(const int* __restrict__ dst, int* __restrict__ deg) {
    int e = blockIdx.x * blockDim.x + threadIdx.x;
    if (e < Ne) atomicAdd(&deg[dst[e]], 1);
}

__global__ void k_dinv(const int* __restrict__ deg, float* __restrict__ dinv) {
    int n = blockIdx.x * blockDim.x + threadIdx.x;
    if (n < Nn) dinv[n] = rsqrtf((float)deg[n] + 1.0f);
}

// exclusive scan of deg into row_off (per-block), block sums to bsum
__global__ void k_scanA(const int* __restrict__ deg, int* __restrict__ row_off,
                        int* __restrict__ bsum) {
    __shared__ int s[256];
    int t = threadIdx.x;
    int i = blockIdx.x * 256 + t;
    int v = (i < Nn) ? deg[i] : 0;
    s[t] = v;
    __syncthreads();
    int x = v;
    for (int off = 1; off < 256; off <<= 1) {
        int u = (t >= off) ? s[t - off] : 0;
        __syncthreads();
        x += u;
        s[t] = x;
        __syncthreads();
    }
    if (i < Nn) row_off[i] = x - v;          // exclusive within block
    if (t == 255) bsum[blockIdx.x] = x;      // block total
}

__global__ void k_scanB(int* __restrict__ bsum, int nblk) {
    __shared__ int s[512];
    int t = threadIdx.x;
    int v = (t < nblk) ? bsum[t] : 0;
    s[t] = v;
    __syncthreads();
    int x = v;
    for (int off = 1; off < 512; off <<= 1) {
        int u = (t >= off) ? s[t - off] : 0;
        __syncthreads();
        x += u;
        s[t] = x;
        __syncthreads();
    }
    if (t < nblk) bsum[t] = x - v;           // exclusive block offsets
}

__global__ void k_scanC(int* __restrict__ row_off, const int* __restrict__ bsum,
                        int* __restrict__ cursor) {
    int i = blockIdx.x * 256 + threadIdx.x;
    if (i < Nn) {
        int v = row_off[i] + bsum[blockIdx.x];
        row_off[i] = v;
        cursor[i] = v;
    }
    if (i == 0) row_off[Nn] = Ne;
}

__global__ void k_place(const int* __restrict__ src, const int* __restrict__ dst,
                        const float* __restrict__ dinv, int* __restrict__ cursor,
                        int* __restrict__ esrc, float* __restrict__ ecoef) {
    int e = blockIdx.x * blockDim.x + threadIdx.x;
    if (e >= Ne) return;
    int d = dst[e], s = src[e];
    int pos = atomicAdd(&cursor[d], 1);
    esrc[pos] = s;
    ecoef[pos] = dinv[s] * dinv[d];
}

__global__ void k_pool_cnt(const int* __restrict__ batch, int* __restrict__ cnt) {
    int n = blockIdx.x * blockDim.x + threadIdx.x;
    if (n < Nn) atomicAdd(&cnt[batch[n]], 1);
}

// ---------------- dense kernels ----------------

// h[n][j] = sum_k x[n][k]*we[k][j] + be[j]; lane j holds column j of we
__global__ __launch_bounds__(256) void k_embed(const float* __restrict__ x,
                                               const float* __restrict__ we,
                                               const float* __restrict__ be,
                                               float* __restrict__ h) {
    int lane = threadIdx.x & 63;
    int wid  = blockIdx.x * (blockDim.x >> 6) + (threadIdx.x >> 6);
    int nw   = gridDim.x * (blockDim.x >> 6);
    float w[Fi];
#pragma unroll
    for (int k = 0; k < Fi; k++) w[k] = we[k * Hd + lane];
    float b = be[lane];
    for (int n = wid; n < Nn; n += nw) {
        float xv = (lane < Fi) ? x[n * Fi + lane] : 0.f;
        float acc = b;
#pragma unroll
        for (int k = 0; k < Fi; k++) acc = fmaf(__shfl(xv, k, 64), w[k], acc);
        h[n * Hd + lane] = acc;
    }
}

// hw = h @ W (64x64); lane j holds column j of W
__global__ __launch_bounds__(256) void k_gemm(const float* __restrict__ h,
                                              const float* __restrict__ W,
                                              float* __restrict__ hw) {
    int lane = threadIdx.x & 63;
    int wid  = blockIdx.x * (blockDim.x >> 6) + (threadIdx.x >> 6);
    int nw   = gridDim.x * (blockDim.x >> 6);
    float w[Hd];
#pragma unroll
    for (int k = 0; k < Hd; k++) w[k] = W[k * Hd + lane];
    for (int n = wid; n < Nn; n += nw) {
        float hv = h[n * Hd + lane];
        float acc = 0.f;
#pragma unroll
        for (int k = 0; k < Hd; k++) acc = fmaf(__shfl(hv, k, 64), w[k], acc);
        hw[n * Hd + lane] = acc;
    }
}

// agg[n][:] = hw[n][:]*dinv[n]^2 + b + sum_{e in CSR row n} hw[esrc[e]][:]*ecoef[e]
// 16 lanes per node, float4 per lane
__global__ __launch_bounds__(256) void k_gather(const float* __restrict__ hw,
                                                const float* __restrict__ dinv,
                                                const int* __restrict__ row_off,
                                                const int* __restrict__ esrc,
                                                const float* __restrict__ ecoef,
                                                const float* __restrict__ bias,
                                                float* __restrict__ agg) {
    int g = threadIdx.x >> 4;   // node slot in block (16)
    int l = threadIdx.x & 15;   // lane in node group
    int node = blockIdx.x * 16 + g;
    if (node >= Nn) return;
    float di = dinv[node];
    float sc = di * di;
    const float* hrow = hw + (size_t)node * Hd + l * 4;
    float4 acc;
    acc.x = hrow[0] * sc; acc.y = hrow[1] * sc; acc.z = hrow[2] * sc; acc.w = hrow[3] * sc;
    const float* bp = bias + l * 4;
    acc.x += bp[0]; acc.y += bp[1]; acc.z += bp[2]; acc.w += bp[3];

    int e = row_off[node], e1 = row_off[node + 1];
    for (; e + 1 < e1; e += 2) {
        int sa = esrc[e], sb = esrc[e + 1];
        float ca = ecoef[e], cb = ecoef[e + 1];
        const float4 va = *(const float4*)(hw + (size_t)sa * Hd + l * 4);
        const float4 vb = *(const float4*)(hw + (size_t)sb * Hd + l * 4);
        acc.x = fmaf(va.x, ca, acc.x); acc.y = fmaf(va.y, ca, acc.y);
        acc.z = fmaf(va.z, ca, acc.z); acc.w = fmaf(va.w, ca, acc.w);
        acc.x = fmaf(vb.x, cb, acc.x); acc.y = fmaf(vb.y, cb, acc.y);
        acc.z = fmaf(vb.z, cb, acc.z); acc.w = fmaf(vb.w, cb, acc.w);
    }
    if (e < e1) {
        int sa = esrc[e];
        float ca = ecoef[e];
        const float4 va = *(const float4*)(hw + (size_t)sa * Hd + l * 4);
        acc.x = fmaf(va.x, ca, acc.x); acc.y = fmaf(va.y, ca, acc.y);
        acc.z = fmaf(va.z, ca, acc.z); acc.w = fmaf(va.w, ca, acc.w);
    }
    *(float4*)(agg + (size_t)node * Hd + l * 4) = acc;
}

// partial per-channel sum/sumsq of agg -> acc[0:64]=sum, acc[64:128]=sumsq
__global__ __launch_bounds__(256) void k_bnstats(const float* __restrict__ agg,
                                                 float* __restrict__ acc) {
    int t = threadIdx.x;
    int ch = t & 63;
    float s = 0.f, s2 = 0.f;
    long stride = (long)gridDim.x * blockDim.x;
    for (long i = (long)blockIdx.x * blockDim.x + t; i < (long)Nn * Hd; i += stride) {
        float v = agg[i];
        s += v;
        s2 = fmaf(v, v, s2);
    }
    __shared__ float ls[256], ls2[256];
    ls[t] = s; ls2[t] = s2;
    __syncthreads();
    if (t < 64) {
        s  = ls[t] + ls[t + 64] + ls[t + 128] + ls[t + 192];
        s2 = ls2[t] + ls2[t + 64] + ls2[t + 128] + ls2[t + 192];
        atomicAdd(&acc[t], s);
        atomicAdd(&acc[64 + t], s2);
    }
}

__global__ void k_bnfinal(const float* __restrict__ acc, const float* __restrict__ gamma,
                          const float* __restrict__ beta, float* __restrict__ bnsc,
                          float* __restrict__ bnsh) {
    int c = threadIdx.x;
    if (c >= 64) return;
    float mean = acc[c] / (float)Nn;
    float var = acc[64 + c] / (float)Nn - mean * mean;
    var = fmaxf(var, 0.f);
    float sc = gamma[c] * rsqrtf(var + BN_EPS);
    bnsc[c] = sc;
    bnsh[c] = beta[c] - mean * sc;
}

// h = relu(agg*sc+sh) + h   (in-place elementwise)
__global__ __launch_bounds__(256) void k_bnapply(const float* __restrict__ agg,
                                                 const float* __restrict__ sc,
                                                 const float* __restrict__ sh,
                                                 float* __restrict__ h) {
    int i = blockIdx.x * blockDim.x + threadIdx.x;   // float4 index
    if (i >= Nn * 16) return;
    int c4 = (i & 15) * 4;
    float4 a = ((const float4*)agg)[i];
    float4 hv = ((float4*)h)[i];
    const float* sp = sc + c4;
    const float* bp = sh + c4;
    float4 r;
    r.x = fmaxf(fmaf(a.x, sp[0], bp[0]), 0.f) + hv.x;
    r.y = fmaxf(fmaf(a.y, sp[1], bp[1]), 0.f) + hv.y;
    r.z = fmaxf(fmaf(a.z, sp[2], bp[2]), 0.f) + hv.z;
    r.w = fmaxf(fmaf(a.w, sp[3], bp[3]), 0.f) + hv.w;
    ((float4*)h)[i] = r;
}

__global__ __launch_bounds__(256) void k_pool(const float* __restrict__ h,
                                              const int* __restrict__ batch,
                                              float* __restrict__ psums) {
    int i = blockIdx.x * blockDim.x + threadIdx.x;   // float4 index
    if (i >= Nn * 16) return;
    int node = i >> 4;
    int c4 = (i & 15) * 4;
    int g = batch[node];
    float4 v = ((const float4*)h)[i];
    float* d = psums + g * Hd + c4;
    atomicAdd(d + 0, v.x);
    atomicAdd(d + 1, v.y);
    atomicAdd(d + 2, v.z);
    atomicAdd(d + 3, v.w);
}

__global__ __launch_bounds__(256) void k_head(const float* __restrict__ psums,
                                              const int* __restrict__ pcnt,
                                              const float* __restrict__ w1,
                                              const float* __restrict__ b1,
                                              const float* __restrict__ w2,
                                              const float* __restrict__ b2,
                                              float* __restrict__ out) {
    __shared__ float sw1[Hd * 32], sw2[32], sb1[32];
    int t = threadIdx.x;
    for (int i = t; i < Hd * 32; i += 256) sw1[i] = w1[i];
    if (t < 32) { sw2[t] = w2[t]; sb1[t] = b1[t]; }
    __syncthreads();
    // t = graph id (G==256==blockDim)
    float inv = 1.0f / fmaxf((float)pcnt[t], 1.0f);
    float acc2[32];
#pragma unroll
    for (int k = 0; k < 32; k++) acc2[k] = sb1[k];
    for (int j = 0; j < Hd; j++) {
        float pj = psums[t * Hd + j] * inv;
#pragma unroll
        for (int k = 0; k < 32; k++) acc2[k] = fmaf(pj, sw1[j * 32 + k], acc2[k]);
    }
    float o = b2[0];
#pragma unroll
    for (int k = 0; k < 32; k++) o += fmaxf(acc2[k], 0.f) * sw2[k];
    out[t] = o;
}

// ---------------- launch ----------------

extern "C" void kernel_launch(void* const* d_in, const int* in_sizes, int n_in,
                              void* d_out, int out_size, void* d_ws, size_t ws_size,
                              hipStream_t stream) {
    const float* x       = (const float*)d_in[0];
    const int*   eidx    = (const int*)d_in[1];
    const int*   batch   = (const int*)d_in[2];
    const float* w_embed = (const float*)d_in[3];
    const float* b_embed = (const float*)d_in[4];
    const float* conv_W  = (const float*)d_in[5];
    const float* conv_b  = (const float*)d_in[6];
    const float* gamma   = (const float*)d_in[7];
    const float* beta    = (const float*)d_in[8];
    const float* w1      = (const float*)d_in[9];
    const float* b1      = (const float*)d_in[10];
    const float* w2      = (const float*)d_in[11];
    const float* b2      = (const float*)d_in[12];
    const int* src = eidx;
    const int* dst = eidx + Ne;

    char* p = (char*)d_ws;
    auto alloc = [&](size_t bytes) -> void* {
        void* r = (void*)p;
        p += (bytes + 255) / 256 * 256;
        return r;
    };
    float* h       = (float*)alloc((size_t)Nn * Hd * 4);
    float* hw      = (float*)alloc((size_t)Nn * Hd * 4);
    float* agg     = (float*)alloc((size_t)Nn * Hd * 4);
    int*   deg     = (int*)alloc((size_t)Nn * 4);
    int*   row_off = (int*)alloc((size_t)(Nn + 1) * 4);
    int*   cursor  = (int*)alloc((size_t)Nn * 4);
    float* dinv    = (float*)alloc((size_t)Nn * 4);
    int*   bsum    = (int*)alloc(512 * 4);
    int*   esrc    = (int*)alloc((size_t)Ne * 4);
    float* ecoef   = (float*)alloc((size_t)Ne * 4);
    float* bnacc   = (float*)alloc(Ll * 128 * 4);
    float* bnsc    = (float*)alloc(64 * 4);
    float* bnsh    = (float*)alloc(64 * 4);
    float* psums   = (float*)alloc((size_t)Gg * Hd * 4);
    int*   pcnt    = (int*)alloc((size_t)Gg * 4);
    (void)ws_size; (void)in_sizes; (void)n_in; (void)out_size;

    const int NB_E = (Ne + 255) / 256;       // 6250
    const int NB_N = (Nn + 255) / 256;       // 391
    const int NB_V4 = (Nn * 16 + 255) / 256; // 6250
    const int NB_G16 = (Nn + 15) / 16;       // 6250

    hipMemsetAsync(deg, 0, (size_t)Nn * 4, stream);
    hipMemsetAsync(bnacc, 0, Ll * 128 * 4, stream);
    hipMemsetAsync(psums, 0, (size_t)Gg * Hd * 4, stream);
    hipMemsetAsync(pcnt, 0, (size_t)Gg * 4, stream);

    k_deg<<<NB_E, 256, 0, stream>>>(dst, deg);
    k_dinv<<<NB_N, 256, 0, stream>>>(deg, dinv);
    k_scanA<<<NB_N, 256, 0, stream>>>(deg, row_off, bsum);
    k_scanB<<<1, 512, 0, stream>>>(bsum, NB_N);
    k_scanC<<<NB_N, 256, 0, stream>>>(row_off, bsum, cursor);
    k_place<<<NB_E, 256, 0, stream>>>(src, dst, dinv, cursor, esrc, ecoef);
    k_pool_cnt<<<NB_N, 256, 0, stream>>>(batch, pcnt);

    k_embed<<<512, 256, 0, stream>>>(x, w_embed, b_embed, h);

    for (int i = 0; i < Ll; i++) {
        k_gemm<<<1024, 256, 0, stream>>>(h, conv_W + (size_t)i * Hd * Hd, hw);
        k_gather<<<NB_G16, 256, 0, stream>>>(hw, dinv, row_off, esrc, ecoef,
                                             conv_b + (size_t)i * Hd, agg);
        k_bnstats<<<512, 256, 0, stream>>>(agg, bnacc + i * 128);
        k_bnfinal<<<1, 64, 0, stream>>>(bnacc + i * 128, gamma + (size_t)i * Hd,
                                        beta + (size_t)i * Hd, bnsc, bnsh);
        k_bnapply<<<NB_V4, 256, 0, stream>>>(agg, bnsc, bnsh, h);
    }

    k_pool<<<NB_V4, 256, 0, stream>>>(h, batch, psums);
    k_head<<<1, 256, 0, stream>>>(psums, pcnt, w1, b1, w2, b2, (float*)d_out);
}

// Round 2
// 961.124 us; speedup vs baseline: 1.3760x; 1.3760x over previous
//
#include <hip/hip_runtime.h>

#define Nn 100000
#define Ne 1600000
#define Fi 32
#define Hd 64
#define Ll 4
#define Gg 256
#define BN_EPS 1e-5f

// ---------------- setup kernels ----------------

__global__ void k_deg(const int* __restrict__ dst, int* __restrict__ deg) {
    int e = blockIdx.x * blockDim.x + threadIdx.x;
    if (e < Ne) atomicAdd(&deg[dst[e]], 1);
}

__global__ void k_dinv(const int* __restrict__ deg, float* __restrict__ dinv) {
    int n = blockIdx.x * blockDim.x + threadIdx.x;
    if (n < Nn) dinv[n] = rsqrtf((float)deg[n] + 1.0f);
}

// exclusive scan of deg into row_off (per-block), block sums to bsum
__global__ void k_scanA(const int* __restrict__ deg, int* __restrict__ row_off,
                        int* __restrict__ bsum) {
    __shared__ int s[256];
    int t = threadIdx.x;
    int i = blockIdx.x * 256 + t;
    int v = (i < Nn) ? deg[i] : 0;
    s[t] = v;
    __syncthreads();
    int x = v;
    for (int off = 1; off < 256; off <<= 1) {
        int u = (t >= off) ? s[t - off] : 0;
        __syncthreads();
        x += u;
        s[t] = x;
        __syncthreads();
    }
    if (i < Nn) row_off[i] = x - v;          // exclusive within block
    if (t == 255) bsum[blockIdx.x] = x;      // block total
}

__global__ void k_scanB(int* __restrict__ bsum, int nblk) {
    __shared__ int s[512];
    int t = threadIdx.x;
    int v = (t < nblk) ? bsum[t] : 0;
    s[t] = v;
    __syncthreads();
    int x = v;
    for (int off = 1; off < 512; off <<= 1) {
        int u = (t >= off) ? s[t - off] : 0;
        __syncthreads();
        x += u;
        s[t] = x;
        __syncthreads();
    }
    if (t < nblk) bsum[t] = x - v;           // exclusive block offsets
}

__global__ void k_scanC(int* __restrict__ row_off, const int* __restrict__ bsum,
                        int* __restrict__ cursor) {
    int i = blockIdx.x * 256 + threadIdx.x;
    if (i < Nn) {
        int v = row_off[i] + bsum[blockIdx.x];
        row_off[i] = v;
        cursor[i] = v;
    }
    if (i == 0) row_off[Nn] = Ne;
}

__global__ void k_place(const int* __restrict__ src, const int* __restrict__ dst,
                        const float* __restrict__ dinv, int* __restrict__ cursor,
                        int* __restrict__ esrc, float* __restrict__ ecoef) {
    int e = blockIdx.x * blockDim.x + threadIdx.x;
    if (e >= Ne) return;
    int d = dst[e], s = src[e];
    int pos = atomicAdd(&cursor[d], 1);
    esrc[pos] = s;
    ecoef[pos] = dinv[s] * dinv[d];
}

// per-graph node ranges via binary search over sorted batch
__global__ void k_gstart(const int* __restrict__ batch, int* __restrict__ gstart) {
    int g = threadIdx.x;   // 256 threads
    int lo = 0, hi = Nn;
    while (lo < hi) {
        int mid = (lo + hi) >> 1;
        if (batch[mid] < g) lo = mid + 1; else hi = mid;
    }
    gstart[g] = lo;
    if (g == 0) gstart[Gg] = Nn;
}

// ---------------- dense kernels ----------------

// h[n][j] = sum_k x[n][k]*we[k][j] + be[j]; lane j holds column j of we
__global__ __launch_bounds__(256) void k_embed(const float* __restrict__ x,
                                               const float* __restrict__ we,
                                               const float* __restrict__ be,
                                               float* __restrict__ h) {
    int lane = threadIdx.x & 63;
    int wid  = blockIdx.x * (blockDim.x >> 6) + (threadIdx.x >> 6);
    int nw   = gridDim.x * (blockDim.x >> 6);
    float w[Fi];
#pragma unroll
    for (int k = 0; k < Fi; k++) w[k] = we[k * Hd + lane];
    float b = be[lane];
    for (int n = wid; n < Nn; n += nw) {
        float xv = (lane < Fi) ? x[n * Fi + lane] : 0.f;
        float acc = b;
#pragma unroll
        for (int k = 0; k < Fi; k++) acc = fmaf(__shfl(xv, k, 64), w[k], acc);
        h[n * Hd + lane] = acc;
    }
}

// hw = h @ W (64x64); lane j holds column j of W
__global__ __launch_bounds__(256) void k_gemm(const float* __restrict__ h,
                                              const float* __restrict__ W,
                                              float* __restrict__ hw) {
    int lane = threadIdx.x & 63;
    int wid  = blockIdx.x * (blockDim.x >> 6) + (threadIdx.x >> 6);
    int nw   = gridDim.x * (blockDim.x >> 6);
    float w[Hd];
#pragma unroll
    for (int k = 0; k < Hd; k++) w[k] = W[k * Hd + lane];
    for (int n = wid; n < Nn; n += nw) {
        float hv = h[n * Hd + lane];
        float acc = 0.f;
#pragma unroll
        for (int k = 0; k < Hd; k++) acc = fmaf(__shfl(hv, k, 64), w[k], acc);
        hw[n * Hd + lane] = acc;
    }
}

// agg[n][:] = hw[n][:]*dinv[n]^2 + b + sum_{e in CSR row n} hw[esrc[e]][:]*ecoef[e]
// 16 lanes per node, float4 per lane
__global__ __launch_bounds__(256) void k_gather(const float* __restrict__ hw,
                                                const float* __restrict__ dinv,
                                                const int* __restrict__ row_off,
                                                const int* __restrict__ esrc,
                                                const float* __restrict__ ecoef,
                                                const float* __restrict__ bias,
                                                float* __restrict__ agg) {
    int g = threadIdx.x >> 4;   // node slot in block (16)
    int l = threadIdx.x & 15;   // lane in node group
    int node = blockIdx.x * 16 + g;
    if (node >= Nn) return;
    float di = dinv[node];
    float sc = di * di;
    const float* hrow = hw + (size_t)node * Hd + l * 4;
    float4 acc;
    acc.x = hrow[0] * sc; acc.y = hrow[1] * sc; acc.z = hrow[2] * sc; acc.w = hrow[3] * sc;
    const float* bp = bias + l * 4;
    acc.x += bp[0]; acc.y += bp[1]; acc.z += bp[2]; acc.w += bp[3];

    int e = row_off[node], e1 = row_off[node + 1];
    for (; e + 1 < e1; e += 2) {
        int sa = esrc[e], sb = esrc[e + 1];
        float ca = ecoef[e], cb = ecoef[e + 1];
        const float4 va = *(const float4*)(hw + (size_t)sa * Hd + l * 4);
        const float4 vb = *(const float4*)(hw + (size_t)sb * Hd + l * 4);
        acc.x = fmaf(va.x, ca, acc.x); acc.y = fmaf(va.y, ca, acc.y);
        acc.z = fmaf(va.z, ca, acc.z); acc.w = fmaf(va.w, ca, acc.w);
        acc.x = fmaf(vb.x, cb, acc.x); acc.y = fmaf(vb.y, cb, acc.y);
        acc.z = fmaf(vb.z, cb, acc.z); acc.w = fmaf(vb.w, cb, acc.w);
    }
    if (e < e1) {
        int sa = esrc[e];
        float ca = ecoef[e];
        const float4 va = *(const float4*)(hw + (size_t)sa * Hd + l * 4);
        acc.x = fmaf(va.x, ca, acc.x); acc.y = fmaf(va.y, ca, acc.y);
        acc.z = fmaf(va.z, ca, acc.z); acc.w = fmaf(va.w, ca, acc.w);
    }
    *(float4*)(agg + (size_t)node * Hd + l * 4) = acc;
}

// partial per-channel sum/sumsq of agg -> acc[0:64]=sum, acc[64:128]=sumsq
__global__ __launch_bounds__(256) void k_bnstats(const float* __restrict__ agg,
                                                 float* __restrict__ acc) {
    int t = threadIdx.x;
    float s = 0.f, s2 = 0.f;
    long stride = (long)gridDim.x * blockDim.x;
    for (long i = (long)blockIdx.x * blockDim.x + t; i < (long)Nn * Hd; i += stride) {
        float v = agg[i];
        s += v;
        s2 = fmaf(v, v, s2);
    }
    __shared__ float ls[256], ls2[256];
    ls[t] = s; ls2[t] = s2;
    __syncthreads();
    if (t < 64) {
        s  = ls[t] + ls[t + 64] + ls[t + 128] + ls[t + 192];
        s2 = ls2[t] + ls2[t + 64] + ls2[t + 128] + ls2[t + 192];
        atomicAdd(&acc[t], s);
        atomicAdd(&acc[64 + t], s2);
    }
}

__global__ void k_bnfinal(const float* __restrict__ acc, const float* __restrict__ gamma,
                          const float* __restrict__ beta, float* __restrict__ bnsc,
                          float* __restrict__ bnsh) {
    int c = threadIdx.x;
    if (c >= 64) return;
    float mean = acc[c] / (float)Nn;
    float var = acc[64 + c] / (float)Nn - mean * mean;
    var = fmaxf(var, 0.f);
    float sc = gamma[c] * rsqrtf(var + BN_EPS);
    bnsc[c] = sc;
    bnsh[c] = beta[c] - mean * sc;
}

// h = relu(agg*sc+sh) + h   (in-place elementwise)
__global__ __launch_bounds__(256) void k_bnapply(const float* __restrict__ agg,
                                                 const float* __restrict__ sc,
                                                 const float* __restrict__ sh,
                                                 float* __restrict__ h) {
    int i = blockIdx.x * blockDim.x + threadIdx.x;   // float4 index
    if (i >= Nn * 16) return;
    int c4 = (i & 15) * 4;
    float4 a = ((const float4*)agg)[i];
    float4 hv = ((float4*)h)[i];
    const float* sp = sc + c4;
    const float* bp = sh + c4;
    float4 r;
    r.x = fmaxf(fmaf(a.x, sp[0], bp[0]), 0.f) + hv.x;
    r.y = fmaxf(fmaf(a.y, sp[1], bp[1]), 0.f) + hv.y;
    r.z = fmaxf(fmaf(a.z, sp[2], bp[2]), 0.f) + hv.z;
    r.w = fmaxf(fmaf(a.w, sp[3], bp[3]), 0.f) + hv.w;
    ((float4*)h)[i] = r;
}

// one block per graph; contiguous node slab; no atomics. Writes MEAN.
__global__ __launch_bounds__(1024) void k_pool2(const float* __restrict__ h,
                                                const int* __restrict__ gstart,
                                                float* __restrict__ pooled) {
    int g = blockIdx.x;
    int t = threadIdx.x;
    int ch = t & 63, sl = t >> 6;     // 16 slices
    int n0 = gstart[g], n1 = gstart[g + 1];
    float s = 0.f;
    for (int n = n0 + sl; n < n1; n += 16) s += h[(size_t)n * Hd + ch];
    __shared__ float ls[1024];
    ls[t] = s;
    __syncthreads();
    if (t < 64) {
        float acc = 0.f;
#pragma unroll
        for (int k = 0; k < 16; k++) acc += ls[k * 64 + t];
        float cnt = (float)(n1 - n0);
        pooled[g * Hd + t] = acc / fmaxf(cnt, 1.0f);
    }
}

__global__ __launch_bounds__(256) void k_head(const float* __restrict__ pooled,
                                              const float* __restrict__ w1,
                                              const float* __restrict__ b1,
                                              const float* __restrict__ w2,
                                              const float* __restrict__ b2,
                                              float* __restrict__ out) {
    __shared__ float sw1[Hd * 32], sw2[32], sb1[32];
    int t = threadIdx.x;
    for (int i = t; i < Hd * 32; i += 256) sw1[i] = w1[i];
    if (t < 32) { sw2[t] = w2[t]; sb1[t] = b1[t]; }
    __syncthreads();
    // t = graph id (G==256==blockDim)
    float acc2[32];
#pragma unroll
    for (int k = 0; k < 32; k++) acc2[k] = sb1[k];
    for (int j = 0; j < Hd; j++) {
        float pj = pooled[t * Hd + j];
#pragma unroll
        for (int k = 0; k < 32; k++) acc2[k] = fmaf(pj, sw1[j * 32 + k], acc2[k]);
    }
    float o = b2[0];
#pragma unroll
    for (int k = 0; k < 32; k++) o += fmaxf(acc2[k], 0.f) * sw2[k];
    out[t] = o;
}

// ---------------- launch ----------------

extern "C" void kernel_launch(void* const* d_in, const int* in_sizes, int n_in,
                              void* d_out, int out_size, void* d_ws, size_t ws_size,
                              hipStream_t stream) {
    const float* x       = (const float*)d_in[0];
    const int*   eidx    = (const int*)d_in[1];
    const int*   batch   = (const int*)d_in[2];
    const float* w_embed = (const float*)d_in[3];
    const float* b_embed = (const float*)d_in[4];
    const float* conv_W  = (const float*)d_in[5];
    const float* conv_b  = (const float*)d_in[6];
    const float* gamma   = (const float*)d_in[7];
    const float* beta    = (const float*)d_in[8];
    const float* w1      = (const float*)d_in[9];
    const float* b1      = (const float*)d_in[10];
    const float* w2      = (const float*)d_in[11];
    const float* b2      = (const float*)d_in[12];
    const int* src = eidx;
    const int* dst = eidx + Ne;

    char* p = (char*)d_ws;
    auto alloc = [&](size_t bytes) -> void* {
        void* r = (void*)p;
        p += (bytes + 255) / 256 * 256;
        return r;
    };
    float* h       = (float*)alloc((size_t)Nn * Hd * 4);
    float* hw      = (float*)alloc((size_t)Nn * Hd * 4);
    float* agg     = (float*)alloc((size_t)Nn * Hd * 4);
    int*   deg     = (int*)alloc((size_t)Nn * 4);
    int*   row_off = (int*)alloc((size_t)(Nn + 1) * 4);
    int*   cursor  = (int*)alloc((size_t)Nn * 4);
    float* dinv    = (float*)alloc((size_t)Nn * 4);
    int*   bsum    = (int*)alloc(512 * 4);
    int*   esrc    = (int*)alloc((size_t)Ne * 4);
    float* ecoef   = (float*)alloc((size_t)Ne * 4);
    float* bnacc   = (float*)alloc(Ll * 128 * 4);
    float* bnsc    = (float*)alloc(64 * 4);
    float* bnsh    = (float*)alloc(64 * 4);
    float* pooled  = (float*)alloc((size_t)Gg * Hd * 4);
    int*   gstart  = (int*)alloc((size_t)(Gg + 1) * 4);
    (void)ws_size; (void)in_sizes; (void)n_in; (void)out_size;

    const int NB_E = (Ne + 255) / 256;       // 6250
    const int NB_N = (Nn + 255) / 256;       // 391
    const int NB_V4 = (Nn * 16 + 255) / 256; // 6250
    const int NB_G16 = (Nn + 15) / 16;       // 6250

    hipMemsetAsync(deg, 0, (size_t)Nn * 4, stream);
    hipMemsetAsync(bnacc, 0, Ll * 128 * 4, stream);

    k_deg<<<NB_E, 256, 0, stream>>>(dst, deg);
    k_dinv<<<NB_N, 256, 0, stream>>>(deg, dinv);
    k_scanA<<<NB_N, 256, 0, stream>>>(deg, row_off, bsum);
    k_scanB<<<1, 512, 0, stream>>>(bsum, NB_N);
    k_scanC<<<NB_N, 256, 0, stream>>>(row_off, bsum, cursor);
    k_place<<<NB_E, 256, 0, stream>>>(src, dst, dinv, cursor, esrc, ecoef);
    k_gstart<<<1, 256, 0, stream>>>(batch, gstart);

    k_embed<<<512, 256, 0, stream>>>(x, w_embed, b_embed, h);

    for (int i = 0; i < Ll; i++) {
        k_gemm<<<1024, 256, 0, stream>>>(h, conv_W + (size_t)i * Hd * Hd, hw);
        k_gather<<<NB_G16, 256, 0, stream>>>(hw, dinv, row_off, esrc, ecoef,
                                             conv_b + (size_t)i * Hd, agg);
        k_bnstats<<<512, 256, 0, stream>>>(agg, bnacc + i * 128);
        k_bnfinal<<<1, 64, 0, stream>>>(bnacc + i * 128, gamma + (size_t)i * Hd,
                                        beta + (size_t)i * Hd, bnsc, bnsh);
        k_bnapply<<<NB_V4, 256, 0, stream>>>(agg, bnsc, bnsh, h);
    }

    k_pool2<<<Gg, 1024, 0, stream>>>(h, gstart, pooled);
    k_head<<<1, 256, 0, stream>>>(pooled, w1, b1, w2, b2, (float*)d_out);
}

// Round 3
// 850.156 us; speedup vs baseline: 1.5556x; 1.1305x over previous
//
#include <hip/hip_runtime.h>

#define Nn 100000
#define Ne 1600000
#define Fi 32
#define Hd 64
#define Ll 4
#define Gg 256
#define BN_EPS 1e-5f

// ---------------- setup kernels ----------------

__global__ void k_deg(const int* __restrict__ dst, int* __restrict__ deg) {
    int e = blockIdx.x * blockDim.x + threadIdx.x;
    if (e < Ne) atomicAdd(&deg[dst[e]], 1);
}

__global__ void k_dinv(const int* __restrict__ deg, float* __restrict__ dinv) {
    int n = blockIdx.x * blockDim.x + threadIdx.x;
    if (n < Nn) dinv[n] = rsqrtf((float)deg[n] + 1.0f);
}

// exclusive scan of deg into row_off (per-block), block sums to bsum
__global__ void k_scanA(const int* __restrict__ deg, int* __restrict__ row_off,
                        int* __restrict__ bsum) {
    __shared__ int s[256];
    int t = threadIdx.x;
    int i = blockIdx.x * 256 + t;
    int v = (i < Nn) ? deg[i] : 0;
    s[t] = v;
    __syncthreads();
    int x = v;
    for (int off = 1; off < 256; off <<= 1) {
        int u = (t >= off) ? s[t - off] : 0;
        __syncthreads();
        x += u;
        s[t] = x;
        __syncthreads();
    }
    if (i < Nn) row_off[i] = x - v;          // exclusive within block
    if (t == 255) bsum[blockIdx.x] = x;      // block total
}

__global__ void k_scanB(int* __restrict__ bsum, int nblk) {
    __shared__ int s[512];
    int t = threadIdx.x;
    int v = (t < nblk) ? bsum[t] : 0;
    s[t] = v;
    __syncthreads();
    int x = v;
    for (int off = 1; off < 512; off <<= 1) {
        int u = (t >= off) ? s[t - off] : 0;
        __syncthreads();
        x += u;
        s[t] = x;
        __syncthreads();
    }
    if (t < nblk) bsum[t] = x - v;           // exclusive block offsets
}

__global__ void k_scanC(int* __restrict__ row_off, const int* __restrict__ bsum,
                        int* __restrict__ cursor) {
    int i = blockIdx.x * 256 + threadIdx.x;
    if (i < Nn) {
        int v = row_off[i] + bsum[blockIdx.x];
        row_off[i] = v;
        cursor[i] = v;
    }
    if (i == 0) row_off[Nn] = Ne;
}

// scatter only esrc (4B/edge); ecoef recomputed in gather from dinv
__global__ void k_place(const int* __restrict__ src, const int* __restrict__ dst,
                        int* __restrict__ cursor, int* __restrict__ esrc) {
    int e = blockIdx.x * blockDim.x + threadIdx.x;
    if (e >= Ne) return;
    int pos = atomicAdd(&cursor[dst[e]], 1);
    esrc[pos] = src[e];
}

// per-graph node ranges via binary search over sorted batch
__global__ void k_gstart(const int* __restrict__ batch, int* __restrict__ gstart) {
    int g = threadIdx.x;   // 256 threads
    int lo = 0, hi = Nn;
    while (lo < hi) {
        int mid = (lo + hi) >> 1;
        if (batch[mid] < g) lo = mid + 1; else hi = mid;
    }
    gstart[g] = lo;
    if (g == 0) gstart[Gg] = Nn;
}

// ---------------- dense kernels ----------------

// fused: h[n] = x[n]@we + be (kept in regs), write h, hw[n] = h[n]@W0, write hw
__global__ __launch_bounds__(256) void k_embed_gemm(const float* __restrict__ x,
                                                    const float* __restrict__ we,
                                                    const float* __restrict__ be,
                                                    const float* __restrict__ W,
                                                    float* __restrict__ h,
                                                    float* __restrict__ hw) {
    int lane = threadIdx.x & 63;
    int wid  = blockIdx.x * (blockDim.x >> 6) + (threadIdx.x >> 6);
    int nw   = gridDim.x * (blockDim.x >> 6);
    float wE[Fi];
#pragma unroll
    for (int k = 0; k < Fi; k++) wE[k] = we[k * Hd + lane];
    float b = be[lane];
    float w0[Hd];
#pragma unroll
    for (int k = 0; k < Hd; k++) w0[k] = W[k * Hd + lane];
    for (int n = wid; n < Nn; n += nw) {
        float xv = (lane < Fi) ? x[n * Fi + lane] : 0.f;
        float hn = b;
#pragma unroll
        for (int k = 0; k < Fi; k++) hn = fmaf(__shfl(xv, k, 64), wE[k], hn);
        h[n * Hd + lane] = hn;
        float acc = 0.f;
#pragma unroll
        for (int k = 0; k < Hd; k++) acc = fmaf(__shfl(hn, k, 64), w0[k], acc);
        hw[n * Hd + lane] = acc;
    }
}

// fused: hn = relu(agg*sc+sh) + h  (bn-apply of prev layer), write h, hw = hn@W
__global__ __launch_bounds__(256) void k_gemmF(const float* __restrict__ agg,
                                               const float* __restrict__ bnsc,
                                               const float* __restrict__ bnsh,
                                               float* __restrict__ h,
                                               const float* __restrict__ W,
                                               float* __restrict__ hw) {
    int lane = threadIdx.x & 63;
    int wid  = blockIdx.x * (blockDim.x >> 6) + (threadIdx.x >> 6);
    int nw   = gridDim.x * (blockDim.x >> 6);
    float sc = bnsc[lane], shv = bnsh[lane];
    float w[Hd];
#pragma unroll
    for (int k = 0; k < Hd; k++) w[k] = W[k * Hd + lane];
    for (int n = wid; n < Nn; n += nw) {
        float a  = agg[(size_t)n * Hd + lane];
        float ho = h[(size_t)n * Hd + lane];
        float hn = fmaxf(fmaf(a, sc, shv), 0.f) + ho;
        h[(size_t)n * Hd + lane] = hn;
        float acc = 0.f;
#pragma unroll
        for (int k = 0; k < Hd; k++) acc = fmaf(__shfl(hn, k, 64), w[k], acc);
        hw[(size_t)n * Hd + lane] = acc;
    }
}

// gather + on-the-fly coef + fused bn-stats (sharded atomics)
__global__ __launch_bounds__(256) void k_gatherS(const float* __restrict__ hw,
                                                 const float* __restrict__ dinv,
                                                 const int* __restrict__ row_off,
                                                 const int* __restrict__ esrc,
                                                 const float* __restrict__ bias,
                                                 float* __restrict__ agg,
                                                 float* __restrict__ bnacc) {
    int g = threadIdx.x >> 4;   // node slot in block (16)
    int l = threadIdx.x & 15;   // lane in node group
    int node = blockIdx.x * 16 + g;   // Nn % 16 == 0, always valid
    float di = dinv[node];
    float scl = di * di;
    const float* hrow = hw + (size_t)node * Hd + l * 4;
    float4 acc;
    acc.x = hrow[0] * scl; acc.y = hrow[1] * scl; acc.z = hrow[2] * scl; acc.w = hrow[3] * scl;
    const float* bp = bias + l * 4;
    acc.x += bp[0]; acc.y += bp[1]; acc.z += bp[2]; acc.w += bp[3];

    int e = row_off[node], e1 = row_off[node + 1];
    for (; e + 1 < e1; e += 2) {
        int sa = esrc[e], sb = esrc[e + 1];
        float ca = dinv[sa] * di, cb = dinv[sb] * di;
        const float4 va = *(const float4*)(hw + (size_t)sa * Hd + l * 4);
        const float4 vb = *(const float4*)(hw + (size_t)sb * Hd + l * 4);
        acc.x = fmaf(va.x, ca, acc.x); acc.y = fmaf(va.y, ca, acc.y);
        acc.z = fmaf(va.z, ca, acc.z); acc.w = fmaf(va.w, ca, acc.w);
        acc.x = fmaf(vb.x, cb, acc.x); acc.y = fmaf(vb.y, cb, acc.y);
        acc.z = fmaf(vb.z, cb, acc.z); acc.w = fmaf(vb.w, cb, acc.w);
    }
    if (e < e1) {
        int sa = esrc[e];
        float ca = dinv[sa] * di;
        const float4 va = *(const float4*)(hw + (size_t)sa * Hd + l * 4);
        acc.x = fmaf(va.x, ca, acc.x); acc.y = fmaf(va.y, ca, acc.y);
        acc.z = fmaf(va.z, ca, acc.z); acc.w = fmaf(va.w, ca, acc.w);
    }
    *(float4*)(agg + (size_t)node * Hd + l * 4) = acc;

    // bn stats: block reduce over 16 node slots, sharded atomics (64 shards)
    __shared__ float ls[1024];
    ((float4*)ls)[threadIdx.x] = acc;   // layout: ls[g*64 + channel]
    __syncthreads();
    int t = threadIdx.x;
    if (t < 64) {
        float s = 0.f, s2 = 0.f;
#pragma unroll
        for (int gg = 0; gg < 16; gg++) {
            float v = ls[gg * 64 + t];
            s += v;
            s2 = fmaf(v, v, s2);
        }
        float* a = bnacc + (blockIdx.x & 63) * 128;
        atomicAdd(&a[t], s);
        atomicAdd(&a[64 + t], s2);
    }
}

__global__ void k_bnfinal(const float* __restrict__ acc, const float* __restrict__ gamma,
                          const float* __restrict__ beta, float* __restrict__ bnsc,
                          float* __restrict__ bnsh) {
    int c = threadIdx.x;
    if (c >= 64) return;
    float s = 0.f, s2 = 0.f;
    for (int sh = 0; sh < 64; sh++) {
        s  += acc[sh * 128 + c];
        s2 += acc[sh * 128 + 64 + c];
    }
    float mean = s / (float)Nn;
    float var = s2 / (float)Nn - mean * mean;
    var = fmaxf(var, 0.f);
    float sc = gamma[c] * rsqrtf(var + BN_EPS);
    bnsc[c] = sc;
    bnsh[c] = beta[c] - mean * sc;
}

// fused: final bn-apply + relu + residual + per-graph mean pool (no h4 write)
__global__ __launch_bounds__(1024) void k_poolF(const float* __restrict__ agg,
                                                const float* __restrict__ bnsc,
                                                const float* __restrict__ bnsh,
                                                const float* __restrict__ h,
                                                const int* __restrict__ gstart,
                                                float* __restrict__ pooled) {
    int g = blockIdx.x;
    int t = threadIdx.x;
    int ch = t & 63, sl = t >> 6;     // 16 slices
    float sc = bnsc[ch], shv = bnsh[ch];
    int n0 = gstart[g], n1 = gstart[g + 1];
    float s = 0.f;
    for (int n = n0 + sl; n < n1; n += 16) {
        float a  = agg[(size_t)n * Hd + ch];
        float ho = h[(size_t)n * Hd + ch];
        s += fmaxf(fmaf(a, sc, shv), 0.f) + ho;
    }
    __shared__ float ls[1024];
    ls[t] = s;
    __syncthreads();
    if (t < 64) {
        float acc = 0.f;
#pragma unroll
        for (int k = 0; k < 16; k++) acc += ls[k * 64 + t];
        float cnt = (float)(n1 - n0);
        pooled[g * Hd + t] = acc / fmaxf(cnt, 1.0f);
    }
}

__global__ __launch_bounds__(256) void k_head(const float* __restrict__ pooled,
                                              const float* __restrict__ w1,
                                              const float* __restrict__ b1,
                                              const float* __restrict__ w2,
                                              const float* __restrict__ b2,
                                              float* __restrict__ out) {
    __shared__ float sw1[Hd * 32], sw2[32], sb1[32];
    int t = threadIdx.x;
    for (int i = t; i < Hd * 32; i += 256) sw1[i] = w1[i];
    if (t < 32) { sw2[t] = w2[t]; sb1[t] = b1[t]; }
    __syncthreads();
    float acc2[32];
#pragma unroll
    for (int k = 0; k < 32; k++) acc2[k] = sb1[k];
    for (int j = 0; j < Hd; j++) {
        float pj = pooled[t * Hd + j];
#pragma unroll
        for (int k = 0; k < 32; k++) acc2[k] = fmaf(pj, sw1[j * 32 + k], acc2[k]);
    }
    float o = b2[0];
#pragma unroll
    for (int k = 0; k < 32; k++) o += fmaxf(acc2[k], 0.f) * sw2[k];
    out[t] = o;
}

// ---------------- launch ----------------

extern "C" void kernel_launch(void* const* d_in, const int* in_sizes, int n_in,
                              void* d_out, int out_size, void* d_ws, size_t ws_size,
                              hipStream_t stream) {
    const float* x       = (const float*)d_in[0];
    const int*   eidx    = (const int*)d_in[1];
    const int*   batch   = (const int*)d_in[2];
    const float* w_embed = (const float*)d_in[3];
    const float* b_embed = (const float*)d_in[4];
    const float* conv_W  = (const float*)d_in[5];
    const float* conv_b  = (const float*)d_in[6];
    const float* gamma   = (const float*)d_in[7];
    const float* beta    = (const float*)d_in[8];
    const float* w1      = (const float*)d_in[9];
    const float* b1      = (const float*)d_in[10];
    const float* w2      = (const float*)d_in[11];
    const float* b2      = (const float*)d_in[12];
    const int* src = eidx;
    const int* dst = eidx + Ne;

    char* p = (char*)d_ws;
    auto alloc = [&](size_t bytes) -> void* {
        void* r = (void*)p;
        p += (bytes + 255) / 256 * 256;
        return r;
    };
    float* h       = (float*)alloc((size_t)Nn * Hd * 4);
    float* hw      = (float*)alloc((size_t)Nn * Hd * 4);
    float* agg     = (float*)alloc((size_t)Nn * Hd * 4);
    int*   deg     = (int*)alloc((size_t)Nn * 4);
    int*   row_off = (int*)alloc((size_t)(Nn + 1) * 4);
    int*   cursor  = (int*)alloc((size_t)Nn * 4);
    float* dinv    = (float*)alloc((size_t)Nn * 4);
    int*   bsum    = (int*)alloc(512 * 4);
    int*   esrc    = (int*)alloc((size_t)Ne * 4);
    float* bnacc   = (float*)alloc((size_t)Ll * 64 * 128 * 4);  // 64 shards x 128 per layer
    float* bnsc    = (float*)alloc(64 * 4);
    float* bnsh    = (float*)alloc(64 * 4);
    float* pooled  = (float*)alloc((size_t)Gg * Hd * 4);
    int*   gstart  = (int*)alloc((size_t)(Gg + 1) * 4);
    (void)ws_size; (void)in_sizes; (void)n_in; (void)out_size;

    const int NB_E = (Ne + 255) / 256;       // 6250
    const int NB_N = (Nn + 255) / 256;       // 391
    const int NB_G16 = (Nn + 15) / 16;       // 6250

    hipMemsetAsync(deg, 0, (size_t)Nn * 4, stream);
    hipMemsetAsync(bnacc, 0, (size_t)Ll * 64 * 128 * 4, stream);

    k_deg<<<NB_E, 256, 0, stream>>>(dst, deg);
    k_dinv<<<NB_N, 256, 0, stream>>>(deg, dinv);
    k_scanA<<<NB_N, 256, 0, stream>>>(deg, row_off, bsum);
    k_scanB<<<1, 512, 0, stream>>>(bsum, NB_N);
    k_scanC<<<NB_N, 256, 0, stream>>>(row_off, bsum, cursor);
    k_place<<<NB_E, 256, 0, stream>>>(src, dst, cursor, esrc);
    k_gstart<<<1, 256, 0, stream>>>(batch, gstart);

    k_embed_gemm<<<1024, 256, 0, stream>>>(x, w_embed, b_embed, conv_W, h, hw);

    for (int i = 0; i < Ll; i++) {
        if (i > 0)
            k_gemmF<<<1024, 256, 0, stream>>>(agg, bnsc, bnsh, h,
                                              conv_W + (size_t)i * Hd * Hd, hw);
        k_gatherS<<<NB_G16, 256, 0, stream>>>(hw, dinv, row_off, esrc,
                                              conv_b + (size_t)i * Hd, agg,
                                              bnacc + (size_t)i * 64 * 128);
        k_bnfinal<<<1, 64, 0, stream>>>(bnacc + (size_t)i * 64 * 128,
                                        gamma + (size_t)i * Hd,
                                        beta + (size_t)i * Hd, bnsc, bnsh);
    }

    k_poolF<<<Gg, 1024, 0, stream>>>(agg, bnsc, bnsh, h, gstart, pooled);
    k_head<<<1, 256, 0, stream>>>(pooled, w1, b1, w2, b2, (float*)d_out);
}